// Round 2
// 9158.578 us; speedup vs baseline: 1.4381x; 1.4381x over previous
//
#include <hip/hip_runtime.h>
#include <hip/hip_fp16.h>

#define TSTEPS 512
#define NBLK_RNN 256

typedef _Float16 f16x8 __attribute__((ext_vector_type(8)));
typedef float f32x4 __attribute__((ext_vector_type(4)));

__device__ __forceinline__ float tanh_fast(float x) {
  float e = __expf(2.0f * x);
  return 1.0f - 2.0f / (e + 1.0f);
}

// Agent-scope (cross-XCD coherent) ring accesses: sc1 loads/stores bypass the
// non-coherent per-XCD L1/L2 and are served by the coherent LLC. This lets us
// drop the per-step agent fences (L2 writeback+invalidate) entirely.
__device__ __forceinline__ float2 ring_ld(const float* p) {
  unsigned long long raw = __hip_atomic_load((const unsigned long long*)p,
                                             __ATOMIC_RELAXED, __HIP_MEMORY_SCOPE_AGENT);
  union { unsigned long long u; float2 f; } cv;
  cv.u = raw;
  return cv.f;
}

__device__ __forceinline__ void ring_st(float* p, float v) {
  __hip_atomic_store(p, v, __ATOMIC_RELAXED, __HIP_MEMORY_SCOPE_AGENT);
}

// ---------------- fp32 -> fp16 convert (vectorized, grid-stride) ----------------
__global__ void k_cvt(const float* __restrict__ src, __half* __restrict__ dst, int n4) {
  int i = blockIdx.x * blockDim.x + threadIdx.x;
  int stride = gridDim.x * blockDim.x;
  for (; i < n4; i += stride) {
    float4 v = ((const float4*)src)[i];
    __half2* d = (__half2*)(dst + 4 * (size_t)i);
    d[0] = __floats2half2_rn(v.x, v.y);
    d[1] = __floats2half2_rn(v.z, v.w);
  }
}

// ---------------- embedding gather + layernorm (no affine) ----------------
__global__ void k_embln(const int* __restrict__ x, const float* __restrict__ emb,
                        float* __restrict__ xln) {
  int row = blockIdx.x;  // b*T + t
  int tok = x[row];
  const float4* src = (const float4*)(emb + (size_t)tok * 1024);
  float4 v = src[threadIdx.x];
  float s = v.x + v.y + v.z + v.w;
  float q = v.x * v.x + v.y * v.y + v.z * v.z + v.w * v.w;
#pragma unroll
  for (int off = 32; off >= 1; off >>= 1) {
    s += __shfl_xor(s, off);
    q += __shfl_xor(q, off);
  }
  __shared__ float sm[8];
  int wave = threadIdx.x >> 6;
  if ((threadIdx.x & 63) == 0) { sm[wave] = s; sm[wave + 4] = q; }
  __syncthreads();
  float st = sm[0] + sm[1] + sm[2] + sm[3];
  float qt = sm[4] + sm[5] + sm[6] + sm[7];
  float mean = st * (1.0f / 1024.0f);
  float var = qt * (1.0f / 1024.0f) - mean * mean;
  float rs = rsqrtf(var + 1e-5f);
  float4 o;
  o.x = (v.x - mean) * rs; o.y = (v.y - mean) * rs;
  o.z = (v.z - mean) * rs; o.w = (v.w - mean) * rs;
  ((float4*)(xln + (size_t)row * 1024))[threadIdx.x] = o;
}

// ---------------- persistent fused 2-layer RNN recurrence ----------------
// 256 blocks x 256 threads, 1 block/CU. Block owns 4 rows of h0 and 4 rows of h1.
// Waves 0-1 (part A): h0_s = tanh(Wih0*x_s + Whh0*h0_{s-1} + b).
// Waves 2-3 (part B): h1_{s-1} = tanh(Wih1*h0_{s-1} + Whh1*h1_{s-2} + b).
// Cross-block h exchange via agent-scope (sc1) loads/stores -> no cache-flush
// fences; one flag-array grid barrier per step.
// Per-thread k-mapping: k = 2*g + 64*i + j (i in [0,16), j in {0,1}).
__global__ __launch_bounds__(256, 1) void k_rnn(
    const float* __restrict__ xln,
    const float* __restrict__ Wih0, const float* __restrict__ Whh0,
    const float* __restrict__ bih0, const float* __restrict__ bhh0,
    const float* __restrict__ Wih1, const float* __restrict__ Whh1,
    const float* __restrict__ bih1, const float* __restrict__ bhh1,
    float* ring, __half* __restrict__ h1seq, unsigned* slots) {
  const int tid = threadIdx.x;
  const int blk = blockIdx.x;
  const int part = tid >> 7;       // 0 = layer0, 1 = layer1
  const int b2 = (tid >> 5) & 3;
  const int g = tid & 31;          // k-group lane
  const int b_lo = b2, b_hi = b2 + 4;
  const int row0 = blk * 4;

  const float* Wih = part ? Wih1 : Wih0;
  const float* Whh = part ? Whh1 : Whh0;
  const float* bih = part ? bih1 : bih0;
  const float* bhh = part ? bhh1 : bhh0;

  // weight-stationary registers: 4 rows x 64 k-values; wv[r][2i+j] = W[row, 2g+64i+j]
  float wv[4][64];
  float bias[4];
#pragma unroll
  for (int r = 0; r < 4; ++r) {
    const float* wi = Wih + (size_t)(row0 + r) * 1024 + 2 * g;
    const float* wh = Whh + (size_t)(row0 + r) * 1024 + 2 * g;
#pragma unroll
    for (int i = 0; i < 16; ++i) {
      float2 a = *(const float2*)(wi + 64 * i);
      wv[r][2 * i] = a.x;
      wv[r][2 * i + 1] = a.y;
      float2 b = *(const float2*)(wh + 64 * i);
      wv[r][32 + 2 * i] = b.x;
      wv[r][32 + 2 * i + 1] = b.y;
    }
    bias[r] = bih[row0 + r] + bhh[row0 + r];
  }

  float* h0r = ring;          // [2][8][1024]
  float* h1r = ring + 16384;  // [2][8][1024]

  for (int s = 0; s <= TSTEPS; ++s) {
    const bool active = (part == 0) ? (s < TSTEPS) : (s >= 1);
    if (active) {
      float acc[4][2];
#pragma unroll
      for (int r = 0; r < 4; ++r) { acc[r][0] = 0.f; acc[r][1] = 0.f; }

      if (part == 0) {
        // L: xln slice (normal cached loads -- stays hot in L2, no fences now)
        const float* x0 = xln + ((size_t)b_lo * TSTEPS + s) * 1024 + 2 * g;
        const float* x1 = xln + ((size_t)b_hi * TSTEPS + s) * 1024 + 2 * g;
#pragma unroll
        for (int i = 0; i < 16; ++i) {
          float2 v0 = *(const float2*)(x0 + 64 * i);
          float2 v1 = *(const float2*)(x1 + 64 * i);
#pragma unroll
          for (int r = 0; r < 4; ++r) {
            acc[r][0] += wv[r][2 * i] * v0.x + wv[r][2 * i + 1] * v0.y;
            acc[r][1] += wv[r][2 * i] * v1.x + wv[r][2 * i + 1] * v1.y;
          }
        }
        // R: h0_{s-1} from coherent ring
        if (s > 0) {
          const float* h0p = h0r + ((s - 1) & 1) * 8192;
          const float* p0 = h0p + b_lo * 1024 + 2 * g;
          const float* p1 = h0p + b_hi * 1024 + 2 * g;
#pragma unroll
          for (int i = 0; i < 16; ++i) {
            float2 v0 = ring_ld(p0 + 64 * i);
            float2 v1 = ring_ld(p1 + 64 * i);
#pragma unroll
            for (int r = 0; r < 4; ++r) {
              acc[r][0] += wv[r][32 + 2 * i] * v0.x + wv[r][33 + 2 * i] * v0.y;
              acc[r][1] += wv[r][32 + 2 * i] * v1.x + wv[r][33 + 2 * i] * v1.y;
            }
          }
        }
      } else {
        // L: h0_{s-1} from coherent ring
        const float* h0p = h0r + ((s - 1) & 1) * 8192;
        const float* p0 = h0p + b_lo * 1024 + 2 * g;
        const float* p1 = h0p + b_hi * 1024 + 2 * g;
#pragma unroll
        for (int i = 0; i < 16; ++i) {
          float2 v0 = ring_ld(p0 + 64 * i);
          float2 v1 = ring_ld(p1 + 64 * i);
#pragma unroll
          for (int r = 0; r < 4; ++r) {
            acc[r][0] += wv[r][2 * i] * v0.x + wv[r][2 * i + 1] * v0.y;
            acc[r][1] += wv[r][2 * i] * v1.x + wv[r][2 * i + 1] * v1.y;
          }
        }
        // R: h1_{s-2} from coherent ring (parity of s-2 == parity of s)
        if (s > 1) {
          const float* h1p = h1r + (s & 1) * 8192;
          const float* q0 = h1p + b_lo * 1024 + 2 * g;
          const float* q1 = h1p + b_hi * 1024 + 2 * g;
#pragma unroll
          for (int i = 0; i < 16; ++i) {
            float2 v0 = ring_ld(q0 + 64 * i);
            float2 v1 = ring_ld(q1 + 64 * i);
#pragma unroll
            for (int r = 0; r < 4; ++r) {
              acc[r][0] += wv[r][32 + 2 * i] * v0.x + wv[r][33 + 2 * i] * v0.y;
              acc[r][1] += wv[r][32 + 2 * i] * v1.x + wv[r][33 + 2 * i] * v1.y;
            }
          }
        }
      }

      // reduce partial dots across the 32 k-group lanes
#pragma unroll
      for (int r = 0; r < 4; ++r)
#pragma unroll
        for (int c = 0; c < 2; ++c) {
          float v = acc[r][c];
          v += __shfl_xor(v, 1);
          v += __shfl_xor(v, 2);
          v += __shfl_xor(v, 4);
          v += __shfl_xor(v, 8);
          v += __shfl_xor(v, 16);
          acc[r][c] = v;
        }
      if (g == 0) {
        if (part == 0) {
          float* dst = h0r + (s & 1) * 8192;
#pragma unroll
          for (int r = 0; r < 4; ++r) {
            ring_st(&dst[b_lo * 1024 + row0 + r], tanh_fast(acc[r][0] + bias[r]));
            ring_st(&dst[b_hi * 1024 + row0 + r], tanh_fast(acc[r][1] + bias[r]));
          }
        } else {
          float* dst = h1r + ((s - 1) & 1) * 8192;
          const int t = s - 1;
#pragma unroll
          for (int r = 0; r < 4; ++r) {
            float hv0 = tanh_fast(acc[r][0] + bias[r]);
            float hv1 = tanh_fast(acc[r][1] + bias[r]);
            ring_st(&dst[b_lo * 1024 + row0 + r], hv0);
            ring_st(&dst[b_hi * 1024 + row0 + r], hv1);
            h1seq[((size_t)b_lo * TSTEPS + t) * 1024 + row0 + r] = __float2half(hv0);
            h1seq[((size_t)b_hi * TSTEPS + t) * 1024 + row0 + r] = __float2half(hv1);
          }
        }
      }
    }
    // ---- grid barrier: __syncthreads drains vmcnt(0) for all waves (sc1 stores
    // are at the coherent point), then post slot, poll all 256 slots. No cache
    // flush/invalidate fences needed: ring traffic bypasses L1/L2.
    __syncthreads();
    if (tid == 0) {
      asm volatile("s_waitcnt vmcnt(0)" ::: "memory");  // defensive; syncthreads drained
      __hip_atomic_store(&slots[blk], (unsigned)(s + 1), __ATOMIC_RELAXED,
                         __HIP_MEMORY_SCOPE_AGENT);
    }
    const unsigned tgt = (unsigned)(s + 1);
    while (__hip_atomic_load(&slots[tid], __ATOMIC_RELAXED,
                             __HIP_MEMORY_SCOPE_AGENT) < tgt) {}
    __syncthreads();
  }
}

// ---------------- fp16 MFMA GEMM: C[M,N] = A[M,K] * B[N,K]^T (+bias,relu) ----------------
// MODE 1: += bias, relu, store half. MODE 0: store float.
template <int MODE>
__global__ __launch_bounds__(256) void k_gemm(const __half* __restrict__ A,
                                              const __half* __restrict__ B,
                                              const float* __restrict__ bias,
                                              void* __restrict__ Cout, int M, int N,
                                              int K) {
  __shared__ __half As[128 * 32];
  __shared__ __half Bs[128 * 32];
  const int tid = threadIdx.x;
  const int m0 = blockIdx.y * 128;
  const int n0 = blockIdx.x * 128;
  const int lane = tid & 63;
  const int wave = tid >> 6;
  const int wy = wave >> 1, wx = wave & 1;
  const int fr = lane & 15, q = lane >> 4;

  const int srow = tid >> 1;
  const int skc = (tid & 1) * 16;
  const __half* Ag = A + (size_t)(m0 + srow) * K + skc;
  const __half* Bg = B + (size_t)(n0 + srow) * K + skc;
  __half* Asw = &As[srow * 32 + skc];
  __half* Bsw = &Bs[srow * 32 + skc];

  f32x4 acc[4][4];
#pragma unroll
  for (int i = 0; i < 4; ++i)
#pragma unroll
    for (int j = 0; j < 4; ++j) acc[i][j] = (f32x4){0.f, 0.f, 0.f, 0.f};

  for (int k0 = 0; k0 < K; k0 += 32) {
    int4 a0 = *(const int4*)Ag;
    int4 a1 = *(const int4*)(Ag + 8);
    int4 b0 = *(const int4*)Bg;
    int4 b1 = *(const int4*)(Bg + 8);
    *(int4*)Asw = a0;
    *(int4*)(Asw + 8) = a1;
    *(int4*)Bsw = b0;
    *(int4*)(Bsw + 8) = b1;
    __syncthreads();
    f16x8 af[4], bf[4];
#pragma unroll
    for (int i = 0; i < 4; ++i)
      af[i] = *(const f16x8*)&As[(wy * 64 + i * 16 + fr) * 32 + q * 8];
#pragma unroll
    for (int j = 0; j < 4; ++j)
      bf[j] = *(const f16x8*)&Bs[(wx * 64 + j * 16 + fr) * 32 + q * 8];
#pragma unroll
    for (int i = 0; i < 4; ++i)
#pragma unroll
      for (int j = 0; j < 4; ++j)
        acc[i][j] = __builtin_amdgcn_mfma_f32_16x16x32_f16(af[i], bf[j], acc[i][j], 0, 0, 0);
    __syncthreads();
    Ag += 32;
    Bg += 32;
  }

  // C/D layout: col = lane&15, row = (lane>>4)*4 + reg  [m89-verified]
  const int rb = q * 4;
#pragma unroll
  for (int i = 0; i < 4; ++i) {
#pragma unroll
    for (int j = 0; j < 4; ++j) {
      int col = n0 + wx * 64 + j * 16 + fr;
      float bv = 0.f;
      if (MODE == 1) bv = bias[col];
#pragma unroll
      for (int r = 0; r < 4; ++r) {
        int row = m0 + wy * 64 + i * 16 + rb + r;
        float v = acc[i][j][r];
        if (MODE == 1) {
          v = fmaxf(v + bv, 0.f);
          ((__half*)Cout)[(size_t)row * N + col] = __float2half(v);
        } else {
          ((float*)Cout)[(size_t)row * N + col] = v;
        }
      }
    }
  }
}

extern "C" void kernel_launch(void* const* d_in, const int* in_sizes, int n_in,
                              void* d_out, int out_size, void* d_ws, size_t ws_size,
                              hipStream_t stream) {
  const int* x = (const int*)d_in[0];
  const float* emb = (const float*)d_in[1];
  const float* Wih0 = (const float*)d_in[2];
  const float* Whh0 = (const float*)d_in[3];
  const float* bih0 = (const float*)d_in[4];
  const float* bhh0 = (const float*)d_in[5];
  const float* Wih1 = (const float*)d_in[6];
  const float* Whh1 = (const float*)d_in[7];
  const float* bih1 = (const float*)d_in[8];
  const float* bhh1 = (const float*)d_in[9];
  const float* Wlin = (const float*)d_in[10];
  const float* blin = (const float*)d_in[11];
  float* out = (float*)d_out;

  // workspace layout (bytes, all 16B-aligned)
  char* w = (char*)d_ws;
  __half* embh = (__half*)(w);                          // 32000*1024*2 = 65,536,000
  __half* wlinh = (__half*)(w + 65536000);              // 1024*1024*2  =  2,097,152
  float* xln = (float*)(w + 67633152);                  // 4096*1024*4  = 16,777,216
  __half* h1seq = (__half*)(w + 84410368);              // 8*512*1024*2 =  8,388,608
  __half* hrelu = (__half*)(w + 92798976);              // 4096*1024*2  =  8,388,608
  float* ring = (float*)(w + 101187584);                // 4*8192*4     =    131,072
  unsigned* slots = (unsigned*)(w + 101318656);         // 256*4 (+pad)
  (void)in_sizes; (void)n_in; (void)out_size; (void)ws_size;

  hipMemsetAsync(slots, 0, 1024, stream);
  k_cvt<<<1024, 256, 0, stream>>>(emb, embh, 32000 * 1024 / 4);
  k_cvt<<<256, 256, 0, stream>>>(Wlin, wlinh, 1024 * 1024 / 4);
  k_embln<<<4096, 256, 0, stream>>>(x, emb, xln);
  k_rnn<<<NBLK_RNN, 256, 0, stream>>>(xln, Wih0, Whh0, bih0, bhh0, Wih1, Whh1, bih1,
                                      bhh1, ring, h1seq, slots);
  k_gemm<1><<<dim3(1024 / 128, 4096 / 128), 256, 0, stream>>>(h1seq, wlinh, blin,
                                                              hrelu, 4096, 1024, 1024);
  k_gemm<0><<<dim3(32000 / 128, 4096 / 128), 256, 0, stream>>>(hrelu, embh, nullptr,
                                                               out, 4096, 32000, 1024);
}

// Round 3
// 5648.057 us; speedup vs baseline: 2.3319x; 1.6215x over previous
//
#include <hip/hip_runtime.h>
#include <hip/hip_fp16.h>

#define TSTEPS 512
#define NBLK_RNN 256

typedef _Float16 f16x8 __attribute__((ext_vector_type(8)));
typedef float f32x4 __attribute__((ext_vector_type(4)));
typedef unsigned u32x4 __attribute__((ext_vector_type(4)));

__device__ __forceinline__ float tanh_fast(float x) {
  float e = __expf(2.0f * x);
  return 1.0f - 2.0f / (e + 1.0f);
}

// Agent-scope store: sc1 write-through to the coherent LLC (bypasses the
// non-coherent per-XCD L1/L2). Paired with sc0+sc1 bypassing LOADS on the
// consumer side -> no cache-flush fences anywhere.
__device__ __forceinline__ void ring_st(float* p, float v) {
  __hip_atomic_store(p, v, __ATOMIC_RELAXED, __HIP_MEMORY_SCOPE_AGENT);
}

// Plain (non-atomic) 16B load with sc0+sc1: bypasses L1/L2, served by coherent
// LLC. Issued as inline asm so the 16 staging loads pipeline (atomic-load
// codegen does not cluster); a single s_waitcnt with "+v" data operands makes
// the consumers depend on post-wait values (rule-#18 hoist hazard avoided).
#define LLC_LD4(dst, ptr) \
  asm volatile("global_load_dwordx4 %0, %1, off sc0 sc1" : "=v"(dst) : "v"(ptr) : "memory")

// ---------------- fp32 -> fp16 convert (vectorized, grid-stride) ----------------
__global__ void k_cvt(const float* __restrict__ src, __half* __restrict__ dst, int n4) {
  int i = blockIdx.x * blockDim.x + threadIdx.x;
  int stride = gridDim.x * blockDim.x;
  for (; i < n4; i += stride) {
    float4 v = ((const float4*)src)[i];
    __half2* d = (__half2*)(dst + 4 * (size_t)i);
    d[0] = __floats2half2_rn(v.x, v.y);
    d[1] = __floats2half2_rn(v.z, v.w);
  }
}

// ---------------- embedding gather + layernorm (no affine) ----------------
__global__ void k_embln(const int* __restrict__ x, const float* __restrict__ emb,
                        float* __restrict__ xln) {
  int row = blockIdx.x;  // b*T + t
  int tok = x[row];
  const float4* src = (const float4*)(emb + (size_t)tok * 1024);
  float4 v = src[threadIdx.x];
  float s = v.x + v.y + v.z + v.w;
  float q = v.x * v.x + v.y * v.y + v.z * v.z + v.w * v.w;
#pragma unroll
  for (int off = 32; off >= 1; off >>= 1) {
    s += __shfl_xor(s, off);
    q += __shfl_xor(q, off);
  }
  __shared__ float sm[8];
  int wave = threadIdx.x >> 6;
  if ((threadIdx.x & 63) == 0) { sm[wave] = s; sm[wave + 4] = q; }
  __syncthreads();
  float st = sm[0] + sm[1] + sm[2] + sm[3];
  float qt = sm[4] + sm[5] + sm[6] + sm[7];
  float mean = st * (1.0f / 1024.0f);
  float var = qt * (1.0f / 1024.0f) - mean * mean;
  float rs = rsqrtf(var + 1e-5f);
  float4 o;
  o.x = (v.x - mean) * rs; o.y = (v.y - mean) * rs;
  o.z = (v.z - mean) * rs; o.w = (v.w - mean) * rs;
  ((float4*)(xln + (size_t)row * 1024))[threadIdx.x] = o;
}

// ---------------- persistent fused 2-layer RNN recurrence ----------------
// 256 blocks x 256 threads, 1 block/CU. Block owns 4 rows of h0 and 4 rows of h1.
// Waves 0-1 (part A): h0_s = tanh(Wih0*x_s + Whh0*h0_{s-1} + b).
// Waves 2-3 (part B): h1_{s-1} = tanh(Wih1*h0_{s-1} + Whh1*h1_{s-2} + b).
// Per step: cooperative LLC->LDS stage of the full h state (one pipelined
// 16x dwordx4 sc0sc1 burst = ONE LLC latency), then all dot-product reads hit
// LDS. Grid barrier: wave-0-only dwordx4 slot poll with s_sleep backoff.
__global__ __launch_bounds__(256, 1) void k_rnn(
    const float* __restrict__ xln,
    const float* __restrict__ Wih0, const float* __restrict__ Whh0,
    const float* __restrict__ bih0, const float* __restrict__ bhh0,
    const float* __restrict__ Wih1, const float* __restrict__ Whh1,
    const float* __restrict__ bih1, const float* __restrict__ bhh1,
    float* ring, __half* __restrict__ h1seq, unsigned* slots) {
  const int tid = threadIdx.x;
  const int blk = blockIdx.x;
  const int part = tid >> 7;       // 0 = layer0, 1 = layer1
  const int b2 = (tid >> 5) & 3;
  const int g = tid & 31;          // k-group lane
  const int b_lo = b2, b_hi = b2 + 4;
  const int row0 = blk * 4;

  const float* Wih = part ? Wih1 : Wih0;
  const float* Whh = part ? Whh1 : Whh0;
  const float* bih = part ? bih1 : bih0;
  const float* bhh = part ? bhh1 : bhh0;

  // weight-stationary registers: 4 rows x 64 k-values; wv[r][2i+j] = W[row, 2g+64i+j]
  float wv[4][64];
  float bias[4];
#pragma unroll
  for (int r = 0; r < 4; ++r) {
    const float* wi = Wih + (size_t)(row0 + r) * 1024 + 2 * g;
    const float* wh = Whh + (size_t)(row0 + r) * 1024 + 2 * g;
#pragma unroll
    for (int i = 0; i < 16; ++i) {
      float2 a = *(const float2*)(wi + 64 * i);
      wv[r][2 * i] = a.x;
      wv[r][2 * i + 1] = a.y;
      float2 b = *(const float2*)(wh + 64 * i);
      wv[r][32 + 2 * i] = b.x;
      wv[r][32 + 2 * i + 1] = b.y;
    }
    bias[r] = bih[row0 + r] + bhh[row0 + r];
  }

  float* h0r = ring;          // [2][8][1024]
  float* h1r = ring + 16384;  // [2][8][1024]

  // LDS mirrors of the previous-step hidden state (staged once per step)
  __shared__ f32x4 H0v[2048];  // h0_{s-1}: [8 batches][1024]
  __shared__ f32x4 H1v[2048];  // h1_{s-2}: [8 batches][1024]
  const float* H0f = (const float*)H0v;
  const float* H1f = (const float*)H1v;

  for (int s = 0; s <= TSTEPS; ++s) {
    // ---- cooperative stage: LLC -> LDS, one latency for the whole 64 KB ----
    if (s > 0) {
      const f32x4* s0 = (const f32x4*)(h0r + ((s - 1) & 1) * 8192) + tid;
      const f32x4* s1 = (const f32x4*)(h1r + (s & 1) * 8192) + tid;
      f32x4 a0, a1, a2, a3, a4, a5, a6, a7;
      f32x4 c0, c1, c2, c3, c4, c5, c6, c7;
      LLC_LD4(a0, s0);        LLC_LD4(a1, s0 + 256);  LLC_LD4(a2, s0 + 512);
      LLC_LD4(a3, s0 + 768);  LLC_LD4(a4, s0 + 1024); LLC_LD4(a5, s0 + 1280);
      LLC_LD4(a6, s0 + 1536); LLC_LD4(a7, s0 + 1792);
      LLC_LD4(c0, s1);        LLC_LD4(c1, s1 + 256);  LLC_LD4(c2, s1 + 512);
      LLC_LD4(c3, s1 + 768);  LLC_LD4(c4, s1 + 1024); LLC_LD4(c5, s1 + 1280);
      LLC_LD4(c6, s1 + 1536); LLC_LD4(c7, s1 + 1792);
      asm volatile("s_waitcnt vmcnt(0)"
                   : "+v"(a0), "+v"(a1), "+v"(a2), "+v"(a3),
                     "+v"(a4), "+v"(a5), "+v"(a6), "+v"(a7),
                     "+v"(c0), "+v"(c1), "+v"(c2), "+v"(c3),
                     "+v"(c4), "+v"(c5), "+v"(c6), "+v"(c7)
                   :: "memory");
      f32x4* d0 = H0v + tid;
      f32x4* d1 = H1v + tid;
      d0[0] = a0;    d0[256] = a1;  d0[512] = a2;  d0[768] = a3;
      d0[1024] = a4; d0[1280] = a5; d0[1536] = a6; d0[1792] = a7;
      d1[0] = c0;    d1[256] = c1;  d1[512] = c2;  d1[768] = c3;
      d1[1024] = c4; d1[1280] = c5; d1[1536] = c6; d1[1792] = c7;
      __syncthreads();
    }

    const bool active = (part == 0) ? (s < TSTEPS) : (s >= 1);
    if (active) {
      float acc[4][2];
#pragma unroll
      for (int r = 0; r < 4; ++r) { acc[r][0] = 0.f; acc[r][1] = 0.f; }

      if (part == 0) {
        // L: xln slice (normal cached loads -- L2-hot)
        const float* x0 = xln + ((size_t)b_lo * TSTEPS + s) * 1024 + 2 * g;
        const float* x1 = xln + ((size_t)b_hi * TSTEPS + s) * 1024 + 2 * g;
#pragma unroll
        for (int i = 0; i < 16; ++i) {
          float2 v0 = *(const float2*)(x0 + 64 * i);
          float2 v1 = *(const float2*)(x1 + 64 * i);
#pragma unroll
          for (int r = 0; r < 4; ++r) {
            acc[r][0] += wv[r][2 * i] * v0.x + wv[r][2 * i + 1] * v0.y;
            acc[r][1] += wv[r][2 * i] * v1.x + wv[r][2 * i + 1] * v1.y;
          }
        }
        // R: h0_{s-1} from LDS
        if (s > 0) {
          const float2* p0 = (const float2*)(H0f + b_lo * 1024 + 2 * g);
          const float2* p1 = (const float2*)(H0f + b_hi * 1024 + 2 * g);
#pragma unroll
          for (int i = 0; i < 16; ++i) {
            float2 v0 = p0[32 * i];
            float2 v1 = p1[32 * i];
#pragma unroll
            for (int r = 0; r < 4; ++r) {
              acc[r][0] += wv[r][32 + 2 * i] * v0.x + wv[r][33 + 2 * i] * v0.y;
              acc[r][1] += wv[r][32 + 2 * i] * v1.x + wv[r][33 + 2 * i] * v1.y;
            }
          }
        }
      } else {
        // L: h0_{s-1} from LDS
        const float2* p0 = (const float2*)(H0f + b_lo * 1024 + 2 * g);
        const float2* p1 = (const float2*)(H0f + b_hi * 1024 + 2 * g);
#pragma unroll
        for (int i = 0; i < 16; ++i) {
          float2 v0 = p0[32 * i];
          float2 v1 = p1[32 * i];
#pragma unroll
          for (int r = 0; r < 4; ++r) {
            acc[r][0] += wv[r][2 * i] * v0.x + wv[r][2 * i + 1] * v0.y;
            acc[r][1] += wv[r][2 * i] * v1.x + wv[r][2 * i + 1] * v1.y;
          }
        }
        // R: h1_{s-2} from LDS
        if (s > 1) {
          const float2* q0 = (const float2*)(H1f + b_lo * 1024 + 2 * g);
          const float2* q1 = (const float2*)(H1f + b_hi * 1024 + 2 * g);
#pragma unroll
          for (int i = 0; i < 16; ++i) {
            float2 v0 = q0[32 * i];
            float2 v1 = q1[32 * i];
#pragma unroll
            for (int r = 0; r < 4; ++r) {
              acc[r][0] += wv[r][32 + 2 * i] * v0.x + wv[r][33 + 2 * i] * v0.y;
              acc[r][1] += wv[r][32 + 2 * i] * v1.x + wv[r][33 + 2 * i] * v1.y;
            }
          }
        }
      }

      // reduce partial dots across the 32 k-group lanes
#pragma unroll
      for (int r = 0; r < 4; ++r)
#pragma unroll
        for (int c = 0; c < 2; ++c) {
          float v = acc[r][c];
          v += __shfl_xor(v, 1);
          v += __shfl_xor(v, 2);
          v += __shfl_xor(v, 4);
          v += __shfl_xor(v, 8);
          v += __shfl_xor(v, 16);
          acc[r][c] = v;
        }
      if (g == 0) {
        if (part == 0) {
          float* dst = h0r + (s & 1) * 8192;
#pragma unroll
          for (int r = 0; r < 4; ++r) {
            ring_st(&dst[b_lo * 1024 + row0 + r], tanh_fast(acc[r][0] + bias[r]));
            ring_st(&dst[b_hi * 1024 + row0 + r], tanh_fast(acc[r][1] + bias[r]));
          }
        } else {
          float* dst = h1r + ((s - 1) & 1) * 8192;
          const int t = s - 1;
#pragma unroll
          for (int r = 0; r < 4; ++r) {
            float hv0 = tanh_fast(acc[r][0] + bias[r]);
            float hv1 = tanh_fast(acc[r][1] + bias[r]);
            ring_st(&dst[b_lo * 1024 + row0 + r], hv0);
            ring_st(&dst[b_hi * 1024 + row0 + r], hv1);
            h1seq[((size_t)b_lo * TSTEPS + t) * 1024 + row0 + r] = __float2half(hv0);
            h1seq[((size_t)b_hi * TSTEPS + t) * 1024 + row0 + r] = __float2half(hv1);
          }
        }
      }
    }

    // ---- grid barrier ----
    // syncthreads makes each wave drain vmcnt(0) before s_barrier (sc1 stores
    // reach the coherent LLC), then tid0 posts; only wave 0 polls (dwordx4 over
    // all 256 slots, s_sleep backoff); everyone else waits at the 2nd barrier.
    __syncthreads();
    if (tid == 0) {
      asm volatile("s_waitcnt vmcnt(0)" ::: "memory");  // defensive
      __hip_atomic_store(&slots[blk], (unsigned)(s + 1), __ATOMIC_RELAXED,
                         __HIP_MEMORY_SCOPE_AGENT);
    }
    if (tid < 64) {
      const u32x4* sp = (const u32x4*)slots + tid;
      const unsigned tgt = (unsigned)(s + 1);
      for (;;) {
        u32x4 v;
        asm volatile("global_load_dwordx4 %0, %1, off sc0 sc1\n\ts_waitcnt vmcnt(0)"
                     : "=v"(v) : "v"(sp) : "memory");
        unsigned m0 = v.x < v.y ? v.x : v.y;
        unsigned m1 = v.z < v.w ? v.z : v.w;
        unsigned m = m0 < m1 ? m0 : m1;
        if (__all((int)(m >= tgt))) break;
        __builtin_amdgcn_s_sleep(1);
      }
    }
    __syncthreads();
  }
}

// ---------------- fp16 MFMA GEMM: C[M,N] = A[M,K] * B[N,K]^T (+bias,relu) ----------------
// MODE 1: += bias, relu, store half. MODE 0: store float.
template <int MODE>
__global__ __launch_bounds__(256) void k_gemm(const __half* __restrict__ A,
                                              const __half* __restrict__ B,
                                              const float* __restrict__ bias,
                                              void* __restrict__ Cout, int M, int N,
                                              int K) {
  __shared__ __half As[128 * 32];
  __shared__ __half Bs[128 * 32];
  const int tid = threadIdx.x;
  const int m0 = blockIdx.y * 128;
  const int n0 = blockIdx.x * 128;
  const int lane = tid & 63;
  const int wave = tid >> 6;
  const int wy = wave >> 1, wx = wave & 1;
  const int fr = lane & 15, q = lane >> 4;

  const int srow = tid >> 1;
  const int skc = (tid & 1) * 16;
  const __half* Ag = A + (size_t)(m0 + srow) * K + skc;
  const __half* Bg = B + (size_t)(n0 + srow) * K + skc;
  __half* Asw = &As[srow * 32 + skc];
  __half* Bsw = &Bs[srow * 32 + skc];

  f32x4 acc[4][4];
#pragma unroll
  for (int i = 0; i < 4; ++i)
#pragma unroll
    for (int j = 0; j < 4; ++j) acc[i][j] = (f32x4){0.f, 0.f, 0.f, 0.f};

  for (int k0 = 0; k0 < K; k0 += 32) {
    int4 a0 = *(const int4*)Ag;
    int4 a1 = *(const int4*)(Ag + 8);
    int4 b0 = *(const int4*)Bg;
    int4 b1 = *(const int4*)(Bg + 8);
    *(int4*)Asw = a0;
    *(int4*)(Asw + 8) = a1;
    *(int4*)Bsw = b0;
    *(int4*)(Bsw + 8) = b1;
    __syncthreads();
    f16x8 af[4], bf[4];
#pragma unroll
    for (int i = 0; i < 4; ++i)
      af[i] = *(const f16x8*)&As[(wy * 64 + i * 16 + fr) * 32 + q * 8];
#pragma unroll
    for (int j = 0; j < 4; ++j)
      bf[j] = *(const f16x8*)&Bs[(wx * 64 + j * 16 + fr) * 32 + q * 8];
#pragma unroll
    for (int i = 0; i < 4; ++i)
#pragma unroll
      for (int j = 0; j < 4; ++j)
        acc[i][j] = __builtin_amdgcn_mfma_f32_16x16x32_f16(af[i], bf[j], acc[i][j], 0, 0, 0);
    __syncthreads();
    Ag += 32;
    Bg += 32;
  }

  // C/D layout: col = lane&15, row = (lane>>4)*4 + reg  [m89-verified]
  const int rb = q * 4;
#pragma unroll
  for (int i = 0; i < 4; ++i) {
#pragma unroll
    for (int j = 0; j < 4; ++j) {
      int col = n0 + wx * 64 + j * 16 + fr;
      float bv = 0.f;
      if (MODE == 1) bv = bias[col];
#pragma unroll
      for (int r = 0; r < 4; ++r) {
        int row = m0 + wy * 64 + i * 16 + rb + r;
        float v = acc[i][j][r];
        if (MODE == 1) {
          v = fmaxf(v + bv, 0.f);
          ((__half*)Cout)[(size_t)row * N + col] = __float2half(v);
        } else {
          ((float*)Cout)[(size_t)row * N + col] = v;
        }
      }
    }
  }
}

extern "C" void kernel_launch(void* const* d_in, const int* in_sizes, int n_in,
                              void* d_out, int out_size, void* d_ws, size_t ws_size,
                              hipStream_t stream) {
  const int* x = (const int*)d_in[0];
  const float* emb = (const float*)d_in[1];
  const float* Wih0 = (const float*)d_in[2];
  const float* Whh0 = (const float*)d_in[3];
  const float* bih0 = (const float*)d_in[4];
  const float* bhh0 = (const float*)d_in[5];
  const float* Wih1 = (const float*)d_in[6];
  const float* Whh1 = (const float*)d_in[7];
  const float* bih1 = (const float*)d_in[8];
  const float* bhh1 = (const float*)d_in[9];
  const float* Wlin = (const float*)d_in[10];
  const float* blin = (const float*)d_in[11];
  float* out = (float*)d_out;

  // workspace layout (bytes, all 16B-aligned)
  char* w = (char*)d_ws;
  __half* embh = (__half*)(w);                          // 32000*1024*2 = 65,536,000
  __half* wlinh = (__half*)(w + 65536000);              // 1024*1024*2  =  2,097,152
  float* xln = (float*)(w + 67633152);                  // 4096*1024*4  = 16,777,216
  __half* h1seq = (__half*)(w + 84410368);              // 8*512*1024*2 =  8,388,608
  __half* hrelu = (__half*)(w + 92798976);              // 4096*1024*2  =  8,388,608
  float* ring = (float*)(w + 101187584);                // 4*8192*4     =    131,072
  unsigned* slots = (unsigned*)(w + 101318656);         // 256*4 (+pad)
  (void)in_sizes; (void)n_in; (void)out_size; (void)ws_size;

  hipMemsetAsync(slots, 0, 1024, stream);
  k_cvt<<<1024, 256, 0, stream>>>(emb, embh, 32000 * 1024 / 4);
  k_cvt<<<256, 256, 0, stream>>>(Wlin, wlinh, 1024 * 1024 / 4);
  k_embln<<<4096, 256, 0, stream>>>(x, emb, xln);
  k_rnn<<<NBLK_RNN, 256, 0, stream>>>(xln, Wih0, Whh0, bih0, bhh0, Wih1, Whh1, bih1,
                                      bhh1, ring, h1seq, slots);
  k_gemm<1><<<dim3(1024 / 128, 4096 / 128), 256, 0, stream>>>(h1seq, wlinh, blin,
                                                              hrelu, 4096, 1024, 1024);
  k_gemm<0><<<dim3(32000 / 128, 4096 / 128), 256, 0, stream>>>(hrelu, embh, nullptr,
                                                               out, 4096, 32000, 1024);
}